// Round 6
// baseline (19535.410 us; speedup 1.0000x reference)
//
#include <hip/hip_runtime.h>

typedef unsigned short u16;
typedef unsigned u32;
typedef unsigned long long u64;
typedef __bf16 bf16x8 __attribute__((ext_vector_type(8)));
typedef _Float16 half8 __attribute__((ext_vector_type(8)));
typedef _Float16 half2v __attribute__((ext_vector_type(2)));
typedef float f32x4 __attribute__((ext_vector_type(4)));
typedef unsigned uint4v __attribute__((ext_vector_type(4)));
typedef unsigned uint2v __attribute__((ext_vector_type(2)));

__device__ __forceinline__ u16 f2b(float f) {
  unsigned u = __builtin_bit_cast(unsigned, f);
  u = (u + 0x7FFFu + ((u >> 16) & 1u)) >> 16;
  return (u16)u;
}
__device__ __forceinline__ float b2f(u16 h) {
  return __builtin_bit_cast(float, ((unsigned)h) << 16);
}
__device__ __forceinline__ u16 f2h(float f) {
  _Float16 h = (_Float16)f;
  return __builtin_bit_cast(unsigned short, h);
}
__device__ __forceinline__ float sigmoidf_(float x) { return 1.0f / (1.0f + expf(-x)); }
__device__ __forceinline__ float fsig(float x) {
  x = fminf(fmaxf(x, -30.f), 30.f);
  return 1.0f / (1.0f + __expf(-x));
}
__device__ __forceinline__ float ftanh_(float x) {
  x = fminf(fmaxf(x, -15.f), 15.f);
  float e = __expf(2.0f * x);
  return (e - 1.0f) / (e + 1.0f);
}
__device__ __forceinline__ u64 aload(const u64* p) {
  return __hip_atomic_load(p, __ATOMIC_RELAXED, __HIP_MEMORY_SCOPE_AGENT);
}

// f32-accumulating packed fp16 dot product on the VALU pipe (2 MAC/lane/instr).
__device__ __forceinline__ float fdot2_(u32 a, u32 b, float c) {
#if __has_builtin(__builtin_amdgcn_fdot2)
  return __builtin_amdgcn_fdot2(__builtin_bit_cast(half2v, a),
                                __builtin_bit_cast(half2v, b), c, false);
#else
  half2v x = __builtin_bit_cast(half2v, a), y = __builtin_bit_cast(half2v, b);
  return c + (float)x.x * (float)y.x + (float)x.y * (float)y.y;
#endif
}

// L2-coherent (same-XCD only!) exchange primitives: sc0 = miss L1, served by the XCD's L2.
// Correctness gated at runtime by the probe/verdict handshake below — never trusted blindly.
__device__ __forceinline__ u64 l2_load1(const u64* p) {
  uint2v r;
  asm volatile("global_load_dwordx2 %0, %1, off sc0\n\ts_waitcnt vmcnt(0)"
               : "=&v"(r) : "v"(p) : "memory");
  return ((u64)r.y << 32) | (u64)r.x;
}
__device__ __forceinline__ void l2_store(u64* p, u64 v) {
  asm volatile("global_store_dwordx2 %0, %1, off sc0" :: "v"(p), "v"(v) : "memory");
}

// ---------------- generic bf16 MFMA GEMM: C[M,N] = A[M,K] @ B[N,K]^T (+C) (+bias) ----------------
// SLAB: write output in decoder per-block slab layout GihS[bb][m][q*32+jj] (bb=col/32 block)
template <int EPI, bool OUTBF, bool ACC, bool SLAB = false>
__global__ __launch_bounds__(256) void gemm_bt(
    const u16* __restrict__ A, int lda,
    const u16* __restrict__ B, int ldb,
    void* __restrict__ Cout, int ldc,
    const float* __restrict__ bias,
    int M, int N, int K) {
  __shared__ __align__(16) u16 As[64 * 40];
  __shared__ __align__(16) u16 Bs[64 * 40];
  const int t = threadIdx.x;
  const int n0 = blockIdx.x * 64, m0 = blockIdx.y * 64;
  const int wave = t >> 6, lane = t & 63;
  const int wm = (wave >> 1) * 32, wn = (wave & 1) * 32;
  const int quad = lane >> 4, r16 = lane & 15;
  const int srow = t >> 2, scol = (t & 3) * 8;
  f32x4 acc[2][2] = {};
  const u16* ap = A + (size_t)(m0 + srow) * lda + scol;
  const u16* bp = B + (size_t)(n0 + srow) * ldb + scol;
  for (int k0 = 0; k0 < K; k0 += 32) {
    uint4 av = *(const uint4*)(ap + k0);
    uint4 bv = *(const uint4*)(bp + k0);
    __syncthreads();
    *(uint4*)&As[srow * 40 + scol] = av;
    *(uint4*)&Bs[srow * 40 + scol] = bv;
    __syncthreads();
    bf16x8 a0 = *(const bf16x8*)&As[(wm + r16) * 40 + quad * 8];
    bf16x8 a1 = *(const bf16x8*)&As[(wm + 16 + r16) * 40 + quad * 8];
    bf16x8 b0 = *(const bf16x8*)&Bs[(wn + r16) * 40 + quad * 8];
    bf16x8 b1 = *(const bf16x8*)&Bs[(wn + 16 + r16) * 40 + quad * 8];
    acc[0][0] = __builtin_amdgcn_mfma_f32_16x16x32_bf16(a0, b0, acc[0][0], 0, 0, 0);
    acc[0][1] = __builtin_amdgcn_mfma_f32_16x16x32_bf16(a0, b1, acc[0][1], 0, 0, 0);
    acc[1][0] = __builtin_amdgcn_mfma_f32_16x16x32_bf16(a1, b0, acc[1][0], 0, 0, 0);
    acc[1][1] = __builtin_amdgcn_mfma_f32_16x16x32_bf16(a1, b1, acc[1][1], 0, 0, 0);
  }
  for (int mi = 0; mi < 2; mi++)
    for (int ni = 0; ni < 2; ni++)
      for (int r = 0; r < 4; r++) {
        int gm = m0 + wm + mi * 16 + quad * 4 + r;
        int gn = n0 + wn + ni * 16 + r16;
        float v = acc[mi][ni][r];
        size_t idx;
        if (SLAB) {
          int q = gn >> 10, bb = (gn >> 5) & 31, jj = gn & 31;
          idx = ((size_t)bb * 8064 + gm) * 128 + q * 32 + jj;
        } else {
          idx = (size_t)gm * ldc + gn;
        }
        if (ACC) v += ((float*)Cout)[idx];
        if (bias) v += bias[gn];
        if (EPI == 1) v = fmaxf(v, 0.0f);
        if (EPI == 2) v = tanhf(v);
        if (OUTBF) ((u16*)Cout)[idx] = f2b(v);
        else ((float*)Cout)[idx] = v;
      }
}

// ---------------- cosine matrix, hi/lo bf16 split ----------------
__global__ __launch_bounds__(256) void k_cos(u16* __restrict__ Chi, u16* __restrict__ Clo) {
  int gid = blockIdx.x * 256 + threadIdx.x;
  int k = gid >> 10, n = gid & 1023;
  int m = (k * n) & 1023;
  float c = cospif((float)m * (1.0f / 512.0f));
  u16 hi = f2b(c);
  Chi[gid] = hi;
  Clo[gid] = f2b(c - b2f(hi));
}

// ---------------- window extraction (w,s order), hi/lo bf16 split ----------------
__global__ __launch_bounds__(256) void k_win(const float* __restrict__ x,
                                             u16* __restrict__ Whi, u16* __restrict__ Wlo) {
  int gid = blockIdx.x * 256 + threadIdx.x;
  int e = gid * 4;
  int r = e >> 10, n = e & 1023;
  int wI = r >> 7, s = r & 127;
  const float* src = x + (size_t)s * 32768 + wI * 512 + n;
  float4 v = *(const float4*)src;
  float vv[4] = {v.x, v.y, v.z, v.w};
#pragma unroll
  for (int i = 0; i < 4; i++) {
    u16 hi = f2b(vv[i]);
    Whi[e + i] = hi;
    Wlo[e + i] = f2b(vv[i] - b2f(hi));
  }
}

// ---------------- fp32 -> bf16 ----------------
__global__ __launch_bounds__(256) void k_f2bk(const float* __restrict__ src, u16* __restrict__ dst) {
  int gid = blockIdx.x * 256 + threadIdx.x;
  int i = gid * 4;
  float4 v = *(const float4*)(src + i);
  dst[i] = f2b(v.x); dst[i + 1] = f2b(v.y); dst[i + 2] = f2b(v.z); dst[i + 3] = f2b(v.w);
}

// ---------------- permute F (w,s)->(s,w) order ----------------
__global__ __launch_bounds__(256) void k_perm(const u16* __restrict__ F1, u16* __restrict__ F2) {
  int gid = blockIdx.x * 256 + threadIdx.x;
  int ro = gid >> 7, n8 = (gid & 127) * 8;
  int s = ro / 63, wI = ro % 63;
  *(uint4*)&F2[(size_t)ro * 1024 + n8] = *(const uint4*)&F1[(size_t)(wI * 128 + s) * 1024 + n8];
}

// ---------------- encoder LSTM cell (adds precomputed input projection) ----------------
__global__ __launch_bounds__(256) void k_cell_enc(const float* __restrict__ g,
                                                  const u16* __restrict__ gihe, int t0,
                                                  float* __restrict__ c_e,
                                                  u16* __restrict__ At) {
  int gid = blockIdx.x * 256 + threadIdx.x;  // 128*1024
  int s = gid >> 10, j = gid & 1023;
  const float* gr = g + (size_t)s * 4096;
  const u16* er = gihe + (size_t)(t0 * 128 + s) * 4096;
  float iv = sigmoidf_(gr[j] + b2f(er[j]));
  float fv = sigmoidf_(gr[j + 1024] + b2f(er[j + 1024]));
  float gv = tanhf(gr[j + 2048] + b2f(er[j + 2048]));
  float ov = sigmoidf_(gr[j + 3072] + b2f(er[j + 3072]));
  float c = fv * c_e[gid] + iv * gv;
  c_e[gid] = c;
  At[(size_t)s * 1024 + j] = f2b(ov * tanhf(c));
}

// ---------------- decoder init: h buffers, election ctrl, probe/verdict ----------------
__global__ void k_initdec(const float* __restrict__ hmid, u64* __restrict__ hb,
                          int* __restrict__ ctrl, u64* __restrict__ probe,
                          u32* __restrict__ verdict) {
  int gid = blockIdx.x * blockDim.x + threadIdx.x;  // 1024
  if (gid < 512) {
    u32 lo = (u32)f2h(hmid[2 * gid]) | ((u32)f2h(hmid[2 * gid + 1]) << 16);
    hb[gid] = (u64)lo;                              // buffer 0: h_0, tag 0
  } else if (gid < 1024) {
    hb[gid] = 0xFFFFFFFF00000000ull;                // buffer 1: sentinel tag
  }
  if (gid < 9) ctrl[gid] = (gid == 8) ? -1 : 0;     // ctrl[0..7]: per-XCD tickets; ctrl[8]: winner
  if (gid >= 16 && gid < 48) probe[gid - 16] = 0ull;
  if (gid >= 48 && gid < 80) verdict[gid - 48] = 0u;
}

// ---------------- persistent decoder: single-XCD fast path + verified fallback ----------------
// 256 blocks x 1024 threads (16 waves, 4/SIMD; flat-work-group-size 1024 HARD-caps VGPR at 128
// => 1 block/CU, all co-resident). Election: per-XCD device-scope tickets; first XCD to collect
// 32 blocks wins. Winners PROBE the sc0/L2 channel, publish verdicts at agent scope, unanimously
// pick fast sc0 exchange or the agent-scope fallback.
// Worker slot b owns outputs j = b*32..b*32+31 (128 gate-rows of Whh_d). Wave w (of 16) owns
// k-slice 64w..64w+64. HYBRID matvec: gate-i rows on the matrix pipe (2 MFMA tiles x 2 ks),
// f/g/o rows on VALU dot2 (48/lane).
// WEIGHT RESIDENCY (round-6 structural fix): rounds 0-5 showed the allocator spills the weight
// set regardless of hints (round 5: 100 VGPR used of a 256 budget, FETCH unchanged at 71 GB =
// ~9 MB/step of spill/reload + weight re-read traffic saturating fabric — the true pacer).
// Halving the per-thread weight set to 64 VGPRs (afrag 16 + wv 48) puts need (~110) UNDER the
// 128-VGPR hard cap, so residency needs no allocator heroics. Wave-local polling: wave w polls
// its own 32 h-words, publishes to its own hsu segment — no cross-wave ordering needed.
__global__ __launch_bounds__(1024) void dec_persist(
    const float* __restrict__ Whh, const u16* __restrict__ GihS,
    const float* __restrict__ hmid,
    u64* __restrict__ hb, float* __restrict__ hfinal,
    int* __restrict__ ctrl, u64* __restrict__ probe, u32* __restrict__ verdict) {
  const int t = threadIdx.x;
  // hwreg 20 = HW_REG_XCC_ID (gfx940+), offset 0, size 32: imm = 20 | (31<<11) = 63508
  u32 xcd = __builtin_amdgcn_s_getreg(63508) & 7u;
  __shared__ int sslot;
  if (t == 0) {
    int tk = atomicAdd(&ctrl[xcd], 1);
    if (tk == 31) atomicCAS(&ctrl[8], -1, (int)xcd);
    int ch;
    do {
      ch = __hip_atomic_load(&ctrl[8], __ATOMIC_RELAXED, __HIP_MEMORY_SCOPE_AGENT);
    } while (ch < 0);
    sslot = (xcd == (u32)ch && tk < 32) ? tk : -1;
  }
  __syncthreads();
  const int b = sslot;
  if (b < 0) return;

  // ---- probe the sc0/L2 channel (bounded, monotone tags, >= compare) ----
  __shared__ int sok;
  if (t == 0) sok = 1;
  __syncthreads();
  for (int r = 0; r < 8; r++) {
    if (sok) {
      if (t == 0) l2_store(&probe[b], (u64)(0xC0DE0000u + (u32)r));
      if (t < 32) {
        const u64 want = (u64)(0xC0DE0000u + (u32)r);
        bool got = false;
        int lim = (r == 0) ? 30000 : 4000;
        for (int it = 0; it < lim; it++) {
          if (l2_load1(&probe[t]) >= want) { got = true; break; }
        }
        if (!got) sok = 0;
      }
    }
    __syncthreads();
  }
  // ---- unanimous verdict via agent scope (always terminates) ----
  if (t == 0)
    __hip_atomic_store(&verdict[b], sok ? 2u : 1u, __ATOMIC_RELAXED, __HIP_MEMORY_SCOPE_AGENT);
  __shared__ int modef;
  if (t == 0) modef = 2;
  __syncthreads();
  if (t < 32) {
    u32 v;
    do {
      v = __hip_atomic_load(&verdict[t], __ATOMIC_RELAXED, __HIP_MEMORY_SCOPE_AGENT);
    } while (v == 0);
    if (v != 2) atomicMin(&modef, 1);
  }
  __syncthreads();
  const bool fast = (modef == 2);

  const int w = t >> 6, lane = t & 63;
  const int quad = lane >> 4, r16 = lane & 15;
  const int hh = (lane >> 5) & 1, jj = lane & 31;

  // MFMA A-fragments: local rows 0..31 (gate i), wave's k-slice 64w..64w+64
  half8 afrag[2][2];
#pragma unroll
  for (int mt = 0; mt < 2; mt++) {
    int lr = mt * 16 + r16;  // 0..31 -> Whh row = b*32 + lr (gate 0)
    const float* Wr = Whh + (size_t)(b * 32 + lr) * 1024 + 64 * w + quad * 8;
#pragma unroll
    for (int ks = 0; ks < 2; ks++) {
      half8 v;
#pragma unroll
      for (int j = 0; j < 8; j++) v[j] = (_Float16)Wr[ks * 32 + j];
      afrag[mt][ks] = v;
    }
  }
  // VALU weights: local rows 32 + jj + 32*j (j=0..2, gates f/g/o), k-32 half hh of the wave's
  // k-64 slice, packed as f16 pairs: 48 VGPRs/thread.
  u32 wv[3][16];
#pragma unroll
  for (int j = 0; j < 3; j++) {
    const float* Wr = Whh + (size_t)((j + 1) * 1024 + b * 32 + jj) * 1024 + 64 * w + 32 * hh;
#pragma unroll
    for (int i = 0; i < 8; i++) {
      float4 f = *(const float4*)(Wr + 4 * i);
      wv[j][2 * i]     = (u32)f2h(f.x) | ((u32)f2h(f.y) << 16);
      wv[j][2 * i + 1] = (u32)f2h(f.z) | ((u32)f2h(f.w) << 16);
    }
  }

  __shared__ __align__(16) u32 hsu[512];           // h as f16 pairs (full vector)
  __shared__ __align__(16) float gpart[2][16][128];// [buf][wave][local gate-row]
  __shared__ __align__(16) u16 uslab[2][2048];     // [buf][step(16) x 128 gates]

  {  // stage slab 0 (steps 0..15): 2 u16 per thread
    *(u32*)&uslab[0][t * 2] = *(const u32*)(GihS + (size_t)b * 8064 * 128 + t * 2);
  }
  float cst = (t < 32) ? hmid[b * 32 + t] : 0.0f;  // c0 = h0 (fp32 exact)

  int n = 0;
  for (int s = 0; s < 128; s++) {
    for (int wI = 0; wI < 63; wI++, n++) {
      // wave-local poll: wave w needs h words 32w..32w+31; lane l polls word 32w+(l&31)
      // (2 lanes per word), lanes<32 publish to this wave's own hsu segment.
      const u32 tn = (u32)n;
      const u64* p = hb + (size_t)(n & 1) * 512 + 32 * w + (lane & 31);
      u64 v;
      if (fast) {
        do { v = l2_load1(p); } while ((u32)(v >> 32) != tn);
      } else {
        for (;;) {
          v = aload(p);
          if ((u32)(v >> 32) == tn) break;
        }
      }
      if (lane < 32) hsu[32 * w + lane] = (u32)v;

      // issue next-slab prefetch under the compute shadow (once per 16 steps)
      const bool slabload = (n & 15) == 0;
      u32 gsv;
      if (slabload) {
        int nn = (n + 16 <= 8048) ? n + 16 : 8048;
        gsv = *(const u32*)(GihS + ((size_t)b * 8064 + nn) * 128 + t * 2);
      }

      // hybrid matvec over this wave's k-64: MFMA (rows 0..31) + dot2 (rows 32..127).
      // All h operands come from this wave's own hsu segment (written by its own lanes).
      f32x4 acc0 = {0.f, 0.f, 0.f, 0.f}, acc1 = {0.f, 0.f, 0.f, 0.f};
      float accV[3] = {0.f, 0.f, 0.f};
#pragma unroll
      for (int g = 0; g < 2; g++) {
        half8 bfv = *(const half8*)&hsu[32 * w + 16 * g + 4 * quad];
        uint4v h0 = *(const uint4v*)&hsu[32 * w + 16 * hh + 8 * g];
        uint4v h1 = *(const uint4v*)&hsu[32 * w + 16 * hh + 8 * g + 4];
        acc0 = __builtin_amdgcn_mfma_f32_16x16x32_f16(afrag[0][g], bfv, acc0, 0, 0, 0);
        acc1 = __builtin_amdgcn_mfma_f32_16x16x32_f16(afrag[1][g], bfv, acc1, 0, 0, 0);
#pragma unroll
        for (int i2 = 0; i2 < 4; i2++)
#pragma unroll
          for (int j = 0; j < 3; j++)
            accV[j] = fdot2_(wv[j][8 * g + i2], h0[i2], accV[j]);
#pragma unroll
        for (int i2 = 0; i2 < 4; i2++)
#pragma unroll
          for (int j = 0; j < 3; j++)
            accV[j] = fdot2_(wv[j][8 * g + 4 + i2], h1[i2], accV[j]);
      }
      const int pb = n & 1;
      if (r16 == 0) {  // MFMA col-0 carriers: rows quad*4+reg of each tile
        *(f32x4*)&gpart[pb][w][4 * quad] = acc0;
        *(f32x4*)&gpart[pb][w][16 + 4 * quad] = acc1;
      }
#pragma unroll
      for (int j = 0; j < 3; j++) {  // fold the two k-32 halves; lanes<32 carry rows 32+jj+32j
        float sum = accV[j] + __shfl_xor(accV[j], 32);
        if (lane < 32) gpart[pb][w][32 + jj + 32 * j] = sum;
      }
      __syncthreads();
      // slab write AFTER barrier: prior-step readers of the other buffer are provably done
      if (slabload) *(u32*)&uslab[((n >> 4) + 1) & 1][t * 2] = gsv;
      if (w == 0) {  // epilogue on wave 0, 64 lanes: rows lane (i/f) and 64+lane (g/o)
        const int sb = (n >> 4) & 1, so = (n & 15) * 128;
        const int rA = lane, rB = 64 + lane;
        float sA = 0.f, sB = 0.f;
#pragma unroll
        for (int ww = 0; ww < 16; ww++) {
          sA += gpart[pb][ww][rA];
          sB += gpart[pb][ww][rB];
        }
        sA += b2f(uslab[sb][so + rA]);
        sB += b2f(uslab[sb][so + rB]);
        float gA = fsig(sA);                                   // i (lane<32) / f (lane>=32)
        float gB = (lane < 32) ? ftanh_(sB) : fsig(sB);        // g / o
        float fx = __shfl_xor(gA, 32);                          // lanes<32 get f
        float ox = __shfl_xor(gB, 32);                          // lanes<32 get o
        if (lane < 32) {
          cst = fx * cst + gA * gB;
          float h = ox * ftanh_(cst);
          u32 h16 = (u32)f2h(h);
          u32 oth = (u32)__shfl_down((int)h16, 1);
          if ((lane & 1) == 0) {
            u64 word = ((u64)(u32)(n + 1) << 32) | (h16 | (oth << 16));
            u64* dst = &hb[(size_t)((n + 1) & 1) * 512 + b * 16 + (lane >> 1)];
            if (fast) l2_store(dst, word);
            else __hip_atomic_store(dst, word, __ATOMIC_RELAXED, __HIP_MEMORY_SCOPE_AGENT);
          }
          if (wI == 62) hfinal[(size_t)s * 1024 + b * 32 + lane] = h;
        }
      }
    }
  }
}

// ---------------- row-wise log_softmax ----------------
__global__ __launch_bounds__(256) void k_lsm(const float* __restrict__ logits, float* __restrict__ out) {
  int s = blockIdx.x, t = threadIdx.x;
  const float* L = logits + (size_t)s * 1024;
  __shared__ float red[4], red2[4];
  float m = -1e30f;
  for (int i = t; i < 1024; i += 256) m = fmaxf(m, L[i]);
  for (int o = 1; o < 64; o <<= 1) m = fmaxf(m, __shfl_xor(m, o));
  if ((t & 63) == 0) red[t >> 6] = m;
  __syncthreads();
  m = fmaxf(fmaxf(red[0], red[1]), fmaxf(red[2], red[3]));
  float sum = 0.f;
  for (int i = t; i < 1024; i += 256) sum += expf(L[i] - m);
  for (int o = 1; o < 64; o <<= 1) sum += __shfl_xor(sum, o);
  if ((t & 63) == 0) red2[t >> 6] = sum;
  __syncthreads();
  sum = red2[0] + red2[1] + red2[2] + red2[3];
  float lse = m + logf(sum);
  for (int i = t; i < 1024; i += 256) out[(size_t)s * 1024 + i] = L[i] - lse;
}

extern "C" void kernel_launch(void* const* d_in, const int* in_sizes, int n_in,
                              void* d_out, int out_size, void* d_ws, size_t ws_size,
                              hipStream_t stream) {
  const float* x     = (const float*)d_in[0];
  const float* Wih_e = (const float*)d_in[1];
  const float* Whh_e = (const float*)d_in[2];
  const float* b_e   = (const float*)d_in[3];
  const float* Wm1   = (const float*)d_in[4];
  const float* bm1   = (const float*)d_in[5];
  const float* Wm2   = (const float*)d_in[6];
  const float* bm2   = (const float*)d_in[7];
  const float* Wih_d = (const float*)d_in[8];
  const float* Whh_d = (const float*)d_in[9];
  const float* b_d   = (const float*)d_in[10];
  const float* Wo    = (const float*)d_in[11];
  const float* bo    = (const float*)d_in[12];
  float* out = (float*)d_out;

  char* w = (char*)d_ws;
  size_t off = 0;
  auto alloc = [&](size_t bytes) { size_t r = off; off += (bytes + 255) & ~(size_t)255; return r; };
  u16* Chi = (u16*)(w + alloc((size_t)1024 * 1024 * 2));
  u16* Clo = (u16*)(w + alloc((size_t)1024 * 1024 * 2));
  u16* F1  = (u16*)(w + alloc((size_t)8064 * 1024 * 2));
  char* f2slot = w + alloc((size_t)8064 * 1024 * 2);   // Win_hi, later F2
  u16* WinHi = (u16*)f2slot;
  u16* F2    = (u16*)f2slot;
  u16* WinLo = (u16*)(w + alloc((size_t)8064 * 1024 * 2));
  char* gislot = w + alloc((size_t)8064 * 4096 * 2);   // Fgem (fp32 33MB), later GihS (bf16 66MB, slab)
  float* Fgem = (float*)gislot;
  u16* GihS   = (u16*)gislot;
  u16* Gihe = (u16*)(w + alloc((size_t)8064 * 4096 * 2));  // encoder input projections (bf16)
  u16* Wihd  = (u16*)(w + alloc((size_t)4096 * 1024 * 2));
  u16* Wihe  = (u16*)(w + alloc((size_t)4096 * 1024 * 2));
  u16* Whhe  = (u16*)(w + alloc((size_t)4096 * 1024 * 2));
  u16* Wm1b = (u16*)(w + alloc((size_t)1024 * 1024 * 2));
  u16* Wm2b = (u16*)(w + alloc((size_t)1024 * 1024 * 2));
  u16* Wob  = (u16*)(w + alloc((size_t)1024 * 1024 * 2));
  u16* At   = (u16*)(w + alloc((size_t)128 * 1024 * 2));
  float* Ge = (float*)(w + alloc((size_t)128 * 4096 * 4));
  float* Ce = (float*)(w + alloc((size_t)128 * 1024 * 4));
  u16* Mid1 = (u16*)(w + alloc((size_t)128 * 1024 * 2));
  float* Hmid = (float*)(w + alloc((size_t)128 * 1024 * 4));
  u64* Hb = (u64*)(w + alloc((size_t)1024 * 8));
  int* Ctrl = (int*)(w + alloc(256));
  u64* Probe = (u64*)(w + alloc(256));
  u32* Verdict = (u32*)(w + alloc(256));
  float* Hfin = (float*)(w + alloc((size_t)128 * 1024 * 4));
  u16* Hfinb  = (u16*)(w + alloc((size_t)128 * 1024 * 2));
  float* Logit = (float*)(w + alloc((size_t)128 * 1024 * 4));
  (void)ws_size; (void)in_sizes; (void)n_in; (void)out_size;

  hipMemsetAsync(At, 0, (size_t)128 * 1024 * 2, stream);   // h=0 for encoder step 0
  hipMemsetAsync(Ce, 0, (size_t)128 * 1024 * 4, stream);

  // Fourier features: F = windows @ C, hi/lo split for ~fp32 accuracy
  k_cos<<<4096, 256, 0, stream>>>(Chi, Clo);
  k_win<<<8064, 256, 0, stream>>>(x, WinHi, WinLo);
  gemm_bt<0, false, false><<<dim3(16, 126), 256, 0, stream>>>(WinHi, 1024, Chi, 1024, Fgem, 1024, nullptr, 8064, 1024, 1024);
  gemm_bt<0, false, true><<<dim3(16, 126), 256, 0, stream>>>(WinHi, 1024, Clo, 1024, Fgem, 1024, nullptr, 8064, 1024, 1024);
  gemm_bt<0, false, true><<<dim3(16, 126), 256, 0, stream>>>(WinLo, 1024, Chi, 1024, Fgem, 1024, nullptr, 8064, 1024, 1024);
  k_f2bk<<<8064, 256, 0, stream>>>(Fgem, F1);        // F1 bf16, (w,s) order
  k_perm<<<4032, 256, 0, stream>>>(F1, F2);          // F2 bf16, (s,w) order

  // weight conversions
  k_f2bk<<<4096, 256, 0, stream>>>(Wih_d, Wihd);
  k_f2bk<<<4096, 256, 0, stream>>>(Wih_e, Wihe);
  k_f2bk<<<4096, 256, 0, stream>>>(Whh_e, Whhe);
  k_f2bk<<<1024, 256, 0, stream>>>(Wm1, Wm1b);
  k_f2bk<<<1024, 256, 0, stream>>>(Wm2, Wm2b);
  k_f2bk<<<1024, 256, 0, stream>>>(Wo, Wob);

  // batched input projections: decoder (slab layout) + encoder
  gemm_bt<0, true, false, true><<<dim3(64, 126), 256, 0, stream>>>(F2, 1024, Wihd, 1024, GihS, 128, b_d, 8064, 4096, 1024);
  gemm_bt<0, true, false><<<dim3(64, 126), 256, 0, stream>>>(F1, 1024, Wihe, 1024, Gihe, 4096, b_e, 8064, 4096, 1024);

  // encoder: 63 steps of gates = h @ Whh_e^T (+Gihe in cell), then cell
  for (int t = 0; t < 63; t++) {
    gemm_bt<0, false, false><<<dim3(64, 2), 256, 0, stream>>>(At, 1024, Whhe, 1024, Ge, 4096, nullptr, 128, 4096, 1024);
    k_cell_enc<<<512, 256, 0, stream>>>(Ge, Gihe, t, Ce, At);
  }

  // mid MLP: tanh(relu(h_enc @ Wm1^T + bm1) @ Wm2^T + bm2)
  gemm_bt<1, true, false><<<dim3(16, 2), 256, 0, stream>>>(At, 1024, Wm1b, 1024, Mid1, 1024, bm1, 128, 1024, 1024);
  gemm_bt<2, false, false><<<dim3(16, 2), 256, 0, stream>>>(Mid1, 1024, Wm2b, 1024, Hmid, 1024, bm2, 128, 1024, 1024);

  // decoder: election + probe/verdict + single-XCD (or verified fallback) persistent loop
  k_initdec<<<4, 256, 0, stream>>>(Hmid, Hb, Ctrl, Probe, Verdict);
  dec_persist<<<256, 1024, 0, stream>>>(Whh_d, GihS, Hmid, Hb, Hfin, Ctrl, Probe, Verdict);

  // output head: log_softmax(h_final @ Wo^T + bo)
  k_f2bk<<<128, 256, 0, stream>>>(Hfin, Hfinb);
  gemm_bt<0, false, false><<<dim3(16, 2), 256, 0, stream>>>(Hfinb, 1024, Wob, 1024, Logit, 1024, bo, 128, 1024, 1024);
  k_lsm<<<128, 256, 0, stream>>>(Logit, out);
}

// Round 7
// 15487.871 us; speedup vs baseline: 1.2613x; 1.2613x over previous
//
#include <hip/hip_runtime.h>

typedef unsigned short u16;
typedef unsigned u32;
typedef unsigned long long u64;
typedef __bf16 bf16x8 __attribute__((ext_vector_type(8)));
typedef _Float16 half8 __attribute__((ext_vector_type(8)));
typedef _Float16 half2v __attribute__((ext_vector_type(2)));
typedef float f32x4 __attribute__((ext_vector_type(4)));
typedef unsigned uint4v __attribute__((ext_vector_type(4)));
typedef unsigned uint2v __attribute__((ext_vector_type(2)));

__device__ __forceinline__ u16 f2b(float f) {
  unsigned u = __builtin_bit_cast(unsigned, f);
  u = (u + 0x7FFFu + ((u >> 16) & 1u)) >> 16;
  return (u16)u;
}
__device__ __forceinline__ float b2f(u16 h) {
  return __builtin_bit_cast(float, ((unsigned)h) << 16);
}
__device__ __forceinline__ u16 f2h(float f) {
  _Float16 h = (_Float16)f;
  return __builtin_bit_cast(unsigned short, h);
}
__device__ __forceinline__ float sigmoidf_(float x) { return 1.0f / (1.0f + expf(-x)); }
__device__ __forceinline__ float fsig(float x) {
  x = fminf(fmaxf(x, -30.f), 30.f);
  return 1.0f / (1.0f + __expf(-x));
}
__device__ __forceinline__ float ftanh_(float x) {
  x = fminf(fmaxf(x, -15.f), 15.f);
  float e = __expf(2.0f * x);
  return (e - 1.0f) / (e + 1.0f);
}
__device__ __forceinline__ u64 aload(const u64* p) {
  return __hip_atomic_load(p, __ATOMIC_RELAXED, __HIP_MEMORY_SCOPE_AGENT);
}

// f32-accumulating packed fp16 dot product on the VALU pipe (2 MAC/lane/instr).
__device__ __forceinline__ float fdot2_(u32 a, u32 b, float c) {
#if __has_builtin(__builtin_amdgcn_fdot2)
  return __builtin_amdgcn_fdot2(__builtin_bit_cast(half2v, a),
                                __builtin_bit_cast(half2v, b), c, false);
#else
  half2v x = __builtin_bit_cast(half2v, a), y = __builtin_bit_cast(half2v, b);
  return c + (float)x.x * (float)y.x + (float)x.y * (float)y.y;
#endif
}

// Exchange primitives. LOAD: sc0 (bypass L1, served by the XCD's shared L2 — the coherence
// point for same-XCD CUs). STORE: plain (CDNA vector L1 is write-through, so the store still
// reaches L2 promptly) — round-6 counters proved sc0 stores write through to HBM (WRITE_SIZE
// == exchange bytes exactly), and that write-through round trip is the suspected visibility
// pacer. Correctness of plain-store visibility is gated at runtime by the probe/verdict
// handshake below — never trusted blindly.
__device__ __forceinline__ u64 l2_load1(const u64* p) {
  uint2v r;
  asm volatile("global_load_dwordx2 %0, %1, off sc0\n\ts_waitcnt vmcnt(0)"
               : "=&v"(r) : "v"(p) : "memory");
  return ((u64)r.y << 32) | (u64)r.x;
}
__device__ __forceinline__ void l2_store(u64* p, u64 v) {
  asm volatile("global_store_dwordx2 %0, %1, off" :: "v"(p), "v"(v) : "memory");
}

// ---------------- generic bf16 MFMA GEMM: C[M,N] = A[M,K] @ B[N,K]^T (+C) (+bias) ----------------
// SLAB: write output in decoder per-block slab layout GihS[bb][m][q*32+jj] (bb=col/32 block)
template <int EPI, bool OUTBF, bool ACC, bool SLAB = false>
__global__ __launch_bounds__(256) void gemm_bt(
    const u16* __restrict__ A, int lda,
    const u16* __restrict__ B, int ldb,
    void* __restrict__ Cout, int ldc,
    const float* __restrict__ bias,
    int M, int N, int K) {
  __shared__ __align__(16) u16 As[64 * 40];
  __shared__ __align__(16) u16 Bs[64 * 40];
  const int t = threadIdx.x;
  const int n0 = blockIdx.x * 64, m0 = blockIdx.y * 64;
  const int wave = t >> 6, lane = t & 63;
  const int wm = (wave >> 1) * 32, wn = (wave & 1) * 32;
  const int quad = lane >> 4, r16 = lane & 15;
  const int srow = t >> 2, scol = (t & 3) * 8;
  f32x4 acc[2][2] = {};
  const u16* ap = A + (size_t)(m0 + srow) * lda + scol;
  const u16* bp = B + (size_t)(n0 + srow) * ldb + scol;
  for (int k0 = 0; k0 < K; k0 += 32) {
    uint4 av = *(const uint4*)(ap + k0);
    uint4 bv = *(const uint4*)(bp + k0);
    __syncthreads();
    *(uint4*)&As[srow * 40 + scol] = av;
    *(uint4*)&Bs[srow * 40 + scol] = bv;
    __syncthreads();
    bf16x8 a0 = *(const bf16x8*)&As[(wm + r16) * 40 + quad * 8];
    bf16x8 a1 = *(const bf16x8*)&As[(wm + 16 + r16) * 40 + quad * 8];
    bf16x8 b0 = *(const bf16x8*)&Bs[(wn + r16) * 40 + quad * 8];
    bf16x8 b1 = *(const bf16x8*)&Bs[(wn + 16 + r16) * 40 + quad * 8];
    acc[0][0] = __builtin_amdgcn_mfma_f32_16x16x32_bf16(a0, b0, acc[0][0], 0, 0, 0);
    acc[0][1] = __builtin_amdgcn_mfma_f32_16x16x32_bf16(a0, b1, acc[0][1], 0, 0, 0);
    acc[1][0] = __builtin_amdgcn_mfma_f32_16x16x32_bf16(a1, b0, acc[1][0], 0, 0, 0);
    acc[1][1] = __builtin_amdgcn_mfma_f32_16x16x32_bf16(a1, b1, acc[1][1], 0, 0, 0);
  }
  for (int mi = 0; mi < 2; mi++)
    for (int ni = 0; ni < 2; ni++)
      for (int r = 0; r < 4; r++) {
        int gm = m0 + wm + mi * 16 + quad * 4 + r;
        int gn = n0 + wn + ni * 16 + r16;
        float v = acc[mi][ni][r];
        size_t idx;
        if (SLAB) {
          int q = gn >> 10, bb = (gn >> 5) & 31, jj = gn & 31;
          idx = ((size_t)bb * 8064 + gm) * 128 + q * 32 + jj;
        } else {
          idx = (size_t)gm * ldc + gn;
        }
        if (ACC) v += ((float*)Cout)[idx];
        if (bias) v += bias[gn];
        if (EPI == 1) v = fmaxf(v, 0.0f);
        if (EPI == 2) v = tanhf(v);
        if (OUTBF) ((u16*)Cout)[idx] = f2b(v);
        else ((float*)Cout)[idx] = v;
      }
}

// ---------------- cosine matrix, hi/lo bf16 split ----------------
__global__ __launch_bounds__(256) void k_cos(u16* __restrict__ Chi, u16* __restrict__ Clo) {
  int gid = blockIdx.x * 256 + threadIdx.x;
  int k = gid >> 10, n = gid & 1023;
  int m = (k * n) & 1023;
  float c = cospif((float)m * (1.0f / 512.0f));
  u16 hi = f2b(c);
  Chi[gid] = hi;
  Clo[gid] = f2b(c - b2f(hi));
}

// ---------------- window extraction (w,s order), hi/lo bf16 split ----------------
__global__ __launch_bounds__(256) void k_win(const float* __restrict__ x,
                                             u16* __restrict__ Whi, u16* __restrict__ Wlo) {
  int gid = blockIdx.x * 256 + threadIdx.x;
  int e = gid * 4;
  int r = e >> 10, n = e & 1023;
  int wI = r >> 7, s = r & 127;
  const float* src = x + (size_t)s * 32768 + wI * 512 + n;
  float4 v = *(const float4*)src;
  float vv[4] = {v.x, v.y, v.z, v.w};
#pragma unroll
  for (int i = 0; i < 4; i++) {
    u16 hi = f2b(vv[i]);
    Whi[e + i] = hi;
    Wlo[e + i] = f2b(vv[i] - b2f(hi));
  }
}

// ---------------- fp32 -> bf16 ----------------
__global__ __launch_bounds__(256) void k_f2bk(const float* __restrict__ src, u16* __restrict__ dst) {
  int gid = blockIdx.x * 256 + threadIdx.x;
  int i = gid * 4;
  float4 v = *(const float4*)(src + i);
  dst[i] = f2b(v.x); dst[i + 1] = f2b(v.y); dst[i + 2] = f2b(v.z); dst[i + 3] = f2b(v.w);
}

// ---------------- permute F (w,s)->(s,w) order ----------------
__global__ __launch_bounds__(256) void k_perm(const u16* __restrict__ F1, u16* __restrict__ F2) {
  int gid = blockIdx.x * 256 + threadIdx.x;
  int ro = gid >> 7, n8 = (gid & 127) * 8;
  int s = ro / 63, wI = ro % 63;
  *(uint4*)&F2[(size_t)ro * 1024 + n8] = *(const uint4*)&F1[(size_t)(wI * 128 + s) * 1024 + n8];
}

// ---------------- encoder LSTM cell (adds precomputed input projection) ----------------
__global__ __launch_bounds__(256) void k_cell_enc(const float* __restrict__ g,
                                                  const u16* __restrict__ gihe, int t0,
                                                  float* __restrict__ c_e,
                                                  u16* __restrict__ At) {
  int gid = blockIdx.x * 256 + threadIdx.x;  // 128*1024
  int s = gid >> 10, j = gid & 1023;
  const float* gr = g + (size_t)s * 4096;
  const u16* er = gihe + (size_t)(t0 * 128 + s) * 4096;
  float iv = sigmoidf_(gr[j] + b2f(er[j]));
  float fv = sigmoidf_(gr[j + 1024] + b2f(er[j + 1024]));
  float gv = tanhf(gr[j + 2048] + b2f(er[j + 2048]));
  float ov = sigmoidf_(gr[j + 3072] + b2f(er[j + 3072]));
  float c = fv * c_e[gid] + iv * gv;
  c_e[gid] = c;
  At[(size_t)s * 1024 + j] = f2b(ov * tanhf(c));
}

// ---------------- decoder init: h buffers, election ctrl, probe/verdict ----------------
__global__ void k_initdec(const float* __restrict__ hmid, u64* __restrict__ hb,
                          int* __restrict__ ctrl, u64* __restrict__ probe,
                          u32* __restrict__ verdict) {
  int gid = blockIdx.x * blockDim.x + threadIdx.x;  // 1024
  if (gid < 512) {
    u32 lo = (u32)f2h(hmid[2 * gid]) | ((u32)f2h(hmid[2 * gid + 1]) << 16);
    hb[gid] = (u64)lo;                              // buffer 0: h_0, tag 0
  } else if (gid < 1024) {
    hb[gid] = 0xFFFFFFFF00000000ull;                // buffer 1: sentinel tag
  }
  if (gid < 9) ctrl[gid] = (gid == 8) ? -1 : 0;     // ctrl[0..7]: per-XCD tickets; ctrl[8]: winner
  if (gid >= 16 && gid < 48) probe[gid - 16] = 0ull;
  if (gid >= 48 && gid < 80) verdict[gid - 48] = 0u;
}

// ---------------- persistent decoder: single-XCD fast path + verified fallback ----------------
// 256 blocks x 512 threads (8 waves, 2/SIMD). Election: per-XCD device-scope tickets; first XCD
// to collect 32 blocks wins. Winners PROBE the exchange channel (now: plain store + sc0 load),
// publish verdicts at agent scope, unanimously pick the fast path or the agent-scope fallback.
// Worker slot b owns outputs j = b*32..b*32+31 (128 gate-rows of Whh_d). Wave w owns k-eighth
// 128w..128w+128. HYBRID matvec: gate-i rows on the matrix pipe, f/g/o rows on VALU dot2.
// ROUND-7 CHANGE (exchange latency, the measured pacer — ~3000 of ~5000 cy/step):
//  (1) exchange stores are PLAIN (no sc0): round-6 WRITE_SIZE proved sc0 stores write through
//      to HBM; plain stores still reach the shared L2 via the write-through L1, skipping the
//      HBM round trip that gates visibility.
//  (2) s_sleep(1) poll throttle: cuts TCC request contention from 16K pollers ~2-3x.
__global__ __launch_bounds__(512, 2) void dec_persist(
    const float* __restrict__ Whh, const u16* __restrict__ GihS,
    const float* __restrict__ hmid,
    u64* __restrict__ hb, float* __restrict__ hfinal,
    int* __restrict__ ctrl, u64* __restrict__ probe, u32* __restrict__ verdict) {
  const int t = threadIdx.x;
  // hwreg 20 = HW_REG_XCC_ID (gfx940+), offset 0, size 32: imm = 20 | (31<<11) = 63508
  u32 xcd = __builtin_amdgcn_s_getreg(63508) & 7u;
  __shared__ int sslot;
  if (t == 0) {
    int tk = atomicAdd(&ctrl[xcd], 1);
    if (tk == 31) atomicCAS(&ctrl[8], -1, (int)xcd);
    int ch;
    do {
      ch = __hip_atomic_load(&ctrl[8], __ATOMIC_RELAXED, __HIP_MEMORY_SCOPE_AGENT);
    } while (ch < 0);
    sslot = (xcd == (u32)ch && tk < 32) ? tk : -1;
  }
  __syncthreads();
  const int b = sslot;
  if (b < 0) return;

  // ---- probe the exchange channel (bounded, monotone tags, >= compare) ----
  // Tests the ACTUAL fast-path mechanism: plain store -> sc0 load visibility.
  __shared__ int sok;
  if (t == 0) sok = 1;
  __syncthreads();
  for (int r = 0; r < 8; r++) {
    if (sok) {
      if (t == 0) l2_store(&probe[b], (u64)(0xC0DE0000u + (u32)r));
      if (t < 32) {
        const u64 want = (u64)(0xC0DE0000u + (u32)r);
        bool got = false;
        int lim = (r == 0) ? 30000 : 4000;
        for (int it = 0; it < lim; it++) {
          if (l2_load1(&probe[t]) >= want) { got = true; break; }
        }
        if (!got) sok = 0;
      }
    }
    __syncthreads();
  }
  // ---- unanimous verdict via agent scope (always terminates) ----
  if (t == 0)
    __hip_atomic_store(&verdict[b], sok ? 2u : 1u, __ATOMIC_RELAXED, __HIP_MEMORY_SCOPE_AGENT);
  __shared__ int modef;
  if (t == 0) modef = 2;
  __syncthreads();
  if (t < 32) {
    u32 v;
    do {
      v = __hip_atomic_load(&verdict[t], __ATOMIC_RELAXED, __HIP_MEMORY_SCOPE_AGENT);
    } while (v == 0);
    if (v != 2) atomicMin(&modef, 1);
  }
  __syncthreads();
  const bool fast = (modef == 2);

  const int w = t >> 6, lane = t & 63;
  const int quad = lane >> 4, r16 = lane & 15;
  const int hh = lane >> 5, jj = lane & 31;

  // MFMA A-fragments: local rows 0..31 (gate i), wave's k-eighth (128 wide)
  half8 afrag[2][4];
#pragma unroll
  for (int mt = 0; mt < 2; mt++) {
    int lr = mt * 16 + r16;  // 0..31 -> Whh row = b*32 + lr (gate 0)
    const float* Wr = Whh + (size_t)(b * 32 + lr) * 1024 + 128 * w + quad * 8;
#pragma unroll
    for (int ks = 0; ks < 4; ks++) {
      half8 v;
#pragma unroll
      for (int j = 0; j < 8; j++) v[j] = (_Float16)Wr[ks * 32 + j];
      afrag[mt][ks] = v;
    }
  }
  // VALU weights: local rows 32 + jj + 32*j (j=0..2, gates f/g/o), k-half hh (64 wide), f16 pairs
  u32 wv[3][32];
#pragma unroll
  for (int j = 0; j < 3; j++) {
    const float* Wr = Whh + (size_t)((j + 1) * 1024 + b * 32 + jj) * 1024 + 128 * w + 64 * hh;
#pragma unroll
    for (int i = 0; i < 16; i++) {
      float4 f = *(const float4*)(Wr + 4 * i);
      wv[j][2 * i]     = (u32)f2h(f.x) | ((u32)f2h(f.y) << 16);
      wv[j][2 * i + 1] = (u32)f2h(f.z) | ((u32)f2h(f.w) << 16);
    }
  }

  __shared__ __align__(16) u32 hsu[512];          // h as f16 pairs (full vector)
  __shared__ __align__(16) float gpart[2][8][128];// [buf][wave][local gate-row]
  __shared__ __align__(16) u16 uslab[2][2048];    // [buf][step(16) x 128 gates]

  {  // stage slab 0 (steps 0..15)
    uint2v g0 = *(const uint2v*)(GihS + (size_t)b * 8064 * 128 + t * 4);
    *(uint2v*)&uslab[0][t * 4] = g0;
  }
  float cst = (t < 32) ? hmid[b * 32 + t] : 0.0f;  // c0 = h0 (fp32 exact)

  int n = 0;
  for (int s = 0; s < 128; s++) {
    for (int wI = 0; wI < 63; wI++, n++) {
      // poll own word of h_n (word t = h[2t..2t+1], tag = n)
      const u32 tn = (u32)n;
      const u64* p = hb + (size_t)(n & 1) * 512 + t;
      u64 v;
      if (fast) {
        for (;;) {
          v = l2_load1(p);
          if ((u32)(v >> 32) == tn) break;
          __builtin_amdgcn_s_sleep(1);  // throttle poll-request rate (TCC contention)
        }
      } else {
        for (;;) {
          v = aload(p);
          if ((u32)(v >> 32) == tn) break;
        }
      }
      hsu[t] = (u32)v;

      // issue next-slab prefetch under the compute shadow (once per 16 steps)
      const bool slabload = (n & 15) == 0;
      uint2v gsv;
      if (slabload) {
        int nn = (n + 16 <= 8048) ? n + 16 : 8048;
        gsv = *(const uint2v*)(GihS + ((size_t)b * 8064 + nn) * 128 + t * 4);
      }

      // hybrid matvec: MFMA (rows 0..31) interleaved with dot2 (rows 32..127).
      // All h operands come from this wave's own hsu segment (written by this wave's lanes).
      f32x4 acc0 = {0.f, 0.f, 0.f, 0.f}, acc1 = {0.f, 0.f, 0.f, 0.f};
      float accV[3] = {0.f, 0.f, 0.f};
#pragma unroll
      for (int g = 0; g < 4; g++) {
        half8 bfv = *(const half8*)&hsu[64 * w + 16 * g + 4 * quad];
        uint4v h0 = *(const uint4v*)&hsu[64 * w + 32 * hh + 8 * g];
        uint4v h1 = *(const uint4v*)&hsu[64 * w + 32 * hh + 8 * g + 4];
        acc0 = __builtin_amdgcn_mfma_f32_16x16x32_f16(afrag[0][g], bfv, acc0, 0, 0, 0);
        acc1 = __builtin_amdgcn_mfma_f32_16x16x32_f16(afrag[1][g], bfv, acc1, 0, 0, 0);
#pragma unroll
        for (int i2 = 0; i2 < 4; i2++)
#pragma unroll
          for (int j = 0; j < 3; j++)
            accV[j] = fdot2_(wv[j][8 * g + i2], h0[i2], accV[j]);
#pragma unroll
        for (int i2 = 0; i2 < 4; i2++)
#pragma unroll
          for (int j = 0; j < 3; j++)
            accV[j] = fdot2_(wv[j][8 * g + 4 + i2], h1[i2], accV[j]);
      }
      const int pb = n & 1;
      if (r16 == 0) {  // MFMA col-0 carriers: rows quad*4+reg of each tile
        *(f32x4*)&gpart[pb][w][4 * quad] = acc0;
        *(f32x4*)&gpart[pb][w][16 + 4 * quad] = acc1;
      }
#pragma unroll
      for (int j = 0; j < 3; j++) {  // VALU: fold k-halves, lanes<32 carry rows 32+jj+32j
        float sum = accV[j] + __shfl_xor(accV[j], 32);
        if (lane < 32) gpart[pb][w][32 + jj + 32 * j] = sum;
      }
      __syncthreads();
      // slab write AFTER barrier: prior-step readers of the other buffer are provably done
      if (slabload) *(uint2v*)&uslab[((n >> 4) + 1) & 1][t * 4] = gsv;
      if (w == 0) {  // epilogue on wave 0, 64 lanes: rows lane (i/f) and 64+lane (g/o)
        const int sb = (n >> 4) & 1, so = (n & 15) * 128;
        const int rA = lane, rB = 64 + lane;
        float sA = 0.f, sB = 0.f;
#pragma unroll
        for (int ww = 0; ww < 8; ww++) {
          sA += gpart[pb][ww][rA];
          sB += gpart[pb][ww][rB];
        }
        sA += b2f(uslab[sb][so + rA]);
        sB += b2f(uslab[sb][so + rB]);
        float gA = fsig(sA);                                   // i (lane<32) / f (lane>=32)
        float gB = (lane < 32) ? ftanh_(sB) : fsig(sB);        // g / o
        float fx = __shfl_xor(gA, 32);                          // lanes<32 get f
        float ox = __shfl_xor(gB, 32);                          // lanes<32 get o
        if (lane < 32) {
          cst = fx * cst + gA * gB;
          float h = ox * ftanh_(cst);
          u32 h16 = (u32)f2h(h);
          u32 oth = (u32)__shfl_down((int)h16, 1);
          if ((lane & 1) == 0) {
            u64 word = ((u64)(u32)(n + 1) << 32) | (h16 | (oth << 16));
            u64* dst = &hb[(size_t)((n + 1) & 1) * 512 + b * 16 + (lane >> 1)];
            if (fast) l2_store(dst, word);
            else __hip_atomic_store(dst, word, __ATOMIC_RELAXED, __HIP_MEMORY_SCOPE_AGENT);
          }
          if (wI == 62) hfinal[(size_t)s * 1024 + b * 32 + lane] = h;
        }
      }
    }
  }
}

// ---------------- row-wise log_softmax ----------------
__global__ __launch_bounds__(256) void k_lsm(const float* __restrict__ logits, float* __restrict__ out) {
  int s = blockIdx.x, t = threadIdx.x;
  const float* L = logits + (size_t)s * 1024;
  __shared__ float red[4], red2[4];
  float m = -1e30f;
  for (int i = t; i < 1024; i += 256) m = fmaxf(m, L[i]);
  for (int o = 1; o < 64; o <<= 1) m = fmaxf(m, __shfl_xor(m, o));
  if ((t & 63) == 0) red[t >> 6] = m;
  __syncthreads();
  m = fmaxf(fmaxf(red[0], red[1]), fmaxf(red[2], red[3]));
  float sum = 0.f;
  for (int i = t; i < 1024; i += 256) sum += expf(L[i] - m);
  for (int o = 1; o < 64; o <<= 1) sum += __shfl_xor(sum, o);
  if ((t & 63) == 0) red2[t >> 6] = sum;
  __syncthreads();
  sum = red2[0] + red2[1] + red2[2] + red2[3];
  float lse = m + logf(sum);
  for (int i = t; i < 1024; i += 256) out[(size_t)s * 1024 + i] = L[i] - lse;
}

extern "C" void kernel_launch(void* const* d_in, const int* in_sizes, int n_in,
                              void* d_out, int out_size, void* d_ws, size_t ws_size,
                              hipStream_t stream) {
  const float* x     = (const float*)d_in[0];
  const float* Wih_e = (const float*)d_in[1];
  const float* Whh_e = (const float*)d_in[2];
  const float* b_e   = (const float*)d_in[3];
  const float* Wm1   = (const float*)d_in[4];
  const float* bm1   = (const float*)d_in[5];
  const float* Wm2   = (const float*)d_in[6];
  const float* bm2   = (const float*)d_in[7];
  const float* Wih_d = (const float*)d_in[8];
  const float* Whh_d = (const float*)d_in[9];
  const float* b_d   = (const float*)d_in[10];
  const float* Wo    = (const float*)d_in[11];
  const float* bo    = (const float*)d_in[12];
  float* out = (float*)d_out;

  char* w = (char*)d_ws;
  size_t off = 0;
  auto alloc = [&](size_t bytes) { size_t r = off; off += (bytes + 255) & ~(size_t)255; return r; };
  u16* Chi = (u16*)(w + alloc((size_t)1024 * 1024 * 2));
  u16* Clo = (u16*)(w + alloc((size_t)1024 * 1024 * 2));
  u16* F1  = (u16*)(w + alloc((size_t)8064 * 1024 * 2));
  char* f2slot = w + alloc((size_t)8064 * 1024 * 2);   // Win_hi, later F2
  u16* WinHi = (u16*)f2slot;
  u16* F2    = (u16*)f2slot;
  u16* WinLo = (u16*)(w + alloc((size_t)8064 * 1024 * 2));
  char* gislot = w + alloc((size_t)8064 * 4096 * 2);   // Fgem (fp32 33MB), later GihS (bf16 66MB, slab)
  float* Fgem = (float*)gislot;
  u16* GihS   = (u16*)gislot;
  u16* Gihe = (u16*)(w + alloc((size_t)8064 * 4096 * 2));  // encoder input projections (bf16)
  u16* Wihd  = (u16*)(w + alloc((size_t)4096 * 1024 * 2));
  u16* Wihe  = (u16*)(w + alloc((size_t)4096 * 1024 * 2));
  u16* Whhe  = (u16*)(w + alloc((size_t)4096 * 1024 * 2));
  u16* Wm1b = (u16*)(w + alloc((size_t)1024 * 1024 * 2));
  u16* Wm2b = (u16*)(w + alloc((size_t)1024 * 1024 * 2));
  u16* Wob  = (u16*)(w + alloc((size_t)1024 * 1024 * 2));
  u16* At   = (u16*)(w + alloc((size_t)128 * 1024 * 2));
  float* Ge = (float*)(w + alloc((size_t)128 * 4096 * 4));
  float* Ce = (float*)(w + alloc((size_t)128 * 1024 * 4));
  u16* Mid1 = (u16*)(w + alloc((size_t)128 * 1024 * 2));
  float* Hmid = (float*)(w + alloc((size_t)128 * 1024 * 4));
  u64* Hb = (u64*)(w + alloc((size_t)1024 * 8));
  int* Ctrl = (int*)(w + alloc(256));
  u64* Probe = (u64*)(w + alloc(256));
  u32* Verdict = (u32*)(w + alloc(256));
  float* Hfin = (float*)(w + alloc((size_t)128 * 1024 * 4));
  u16* Hfinb  = (u16*)(w + alloc((size_t)128 * 1024 * 2));
  float* Logit = (float*)(w + alloc((size_t)128 * 1024 * 4));
  (void)ws_size; (void)in_sizes; (void)n_in; (void)out_size;

  hipMemsetAsync(At, 0, (size_t)128 * 1024 * 2, stream);   // h=0 for encoder step 0
  hipMemsetAsync(Ce, 0, (size_t)128 * 1024 * 4, stream);

  // Fourier features: F = windows @ C, hi/lo split for ~fp32 accuracy
  k_cos<<<4096, 256, 0, stream>>>(Chi, Clo);
  k_win<<<8064, 256, 0, stream>>>(x, WinHi, WinLo);
  gemm_bt<0, false, false><<<dim3(16, 126), 256, 0, stream>>>(WinHi, 1024, Chi, 1024, Fgem, 1024, nullptr, 8064, 1024, 1024);
  gemm_bt<0, false, true><<<dim3(16, 126), 256, 0, stream>>>(WinHi, 1024, Clo, 1024, Fgem, 1024, nullptr, 8064, 1024, 1024);
  gemm_bt<0, false, true><<<dim3(16, 126), 256, 0, stream>>>(WinLo, 1024, Chi, 1024, Fgem, 1024, nullptr, 8064, 1024, 1024);
  k_f2bk<<<8064, 256, 0, stream>>>(Fgem, F1);        // F1 bf16, (w,s) order
  k_perm<<<4032, 256, 0, stream>>>(F1, F2);          // F2 bf16, (s,w) order

  // weight conversions
  k_f2bk<<<4096, 256, 0, stream>>>(Wih_d, Wihd);
  k_f2bk<<<4096, 256, 0, stream>>>(Wih_e, Wihe);
  k_f2bk<<<4096, 256, 0, stream>>>(Whh_e, Whhe);
  k_f2bk<<<1024, 256, 0, stream>>>(Wm1, Wm1b);
  k_f2bk<<<1024, 256, 0, stream>>>(Wm2, Wm2b);
  k_f2bk<<<1024, 256, 0, stream>>>(Wo, Wob);

  // batched input projections: decoder (slab layout) + encoder
  gemm_bt<0, true, false, true><<<dim3(64, 126), 256, 0, stream>>>(F2, 1024, Wihd, 1024, GihS, 128, b_d, 8064, 4096, 1024);
  gemm_bt<0, true, false><<<dim3(64, 126), 256, 0, stream>>>(F1, 1024, Wihe, 1024, Gihe, 4096, b_e, 8064, 4096, 1024);

  // encoder: 63 steps of gates = h @ Whh_e^T (+Gihe in cell), then cell
  for (int t = 0; t < 63; t++) {
    gemm_bt<0, false, false><<<dim3(64, 2), 256, 0, stream>>>(At, 1024, Whhe, 1024, Ge, 4096, nullptr, 128, 4096, 1024);
    k_cell_enc<<<512, 256, 0, stream>>>(Ge, Gihe, t, Ce, At);
  }

  // mid MLP: tanh(relu(h_enc @ Wm1^T + bm1) @ Wm2^T + bm2)
  gemm_bt<1, true, false><<<dim3(16, 2), 256, 0, stream>>>(At, 1024, Wm1b, 1024, Mid1, 1024, bm1, 128, 1024, 1024);
  gemm_bt<2, false, false><<<dim3(16, 2), 256, 0, stream>>>(Mid1, 1024, Wm2b, 1024, Hmid, 1024, bm2, 128, 1024, 1024);

  // decoder: election + probe/verdict + single-XCD (or verified fallback) persistent loop
  k_initdec<<<4, 256, 0, stream>>>(Hmid, Hb, Ctrl, Probe, Verdict);
  dec_persist<<<256, 512, 0, stream>>>(Whh_d, GihS, Hmid, Hb, Hfin, Ctrl, Probe, Verdict);

  // output head: log_softmax(h_final @ Wo^T + bo)
  k_f2bk<<<128, 256, 0, stream>>>(Hfin, Hfinb);
  gemm_bt<0, false, false><<<dim3(16, 2), 256, 0, stream>>>(Hfinb, 1024, Wob, 1024, Logit, 1024, bo, 128, 1024, 1024);
  k_lsm<<<128, 256, 0, stream>>>(Logit, out);
}